// Round 1
// baseline (218.903 us; speedup 1.0000x reference)
//
#include <hip/hip_runtime.h>
#include <math.h>

// SplatCondenseNet fused tree pooling.
// One block owns 64 consecutive leaves (a full L6 subtree) and computes
// L1(mean), L2(mean), L3..L6(attention over 8) entirely from LDS.
//
// Output layout (rows of 128 fp32, concat of layers 1..6):
//   L1: rows [0,       262144)
//   L2: rows [262144,  393216)
//   L3: rows [393216,  458752)
//   L4: rows [458752,  491520)
//   L5: rows [491520,  507904)
//   L6: rows [507904,  516096)

static constexpr size_t O1 = 0;
static constexpr size_t O2 = 262144ull * 128;
static constexpr size_t O3 = 393216ull * 128;
static constexpr size_t O4 = 458752ull * 128;
static constexpr size_t O5 = 491520ull * 128;
static constexpr size_t O6 = 507904ull * 128;

#define TPB 256

__global__ __launch_bounds__(TPB) void splat_fused(
    const float* __restrict__ x0, const float* __restrict__ w,
    float* __restrict__ out) {
  __shared__ float sx[64 * 128];   // leaf tile
  __shared__ float sl1[32 * 128];  // layer 1
  __shared__ float sl2[16 * 128];  // layer 2
  __shared__ float sl3[8 * 128];   // layer 3
  __shared__ float sw[128];        // attention query
  // score / weight scratch: s3[0..63] s4[64..95] s5[96..111] s6[112..119]
  __shared__ float ssc[120];
  __shared__ float swt[120];

  const int tid = threadIdx.x;
  const int lane = tid & 63;
  const int wid = tid >> 6;
  const int b = blockIdx.x;

  // ---- load 64x128 tile (float4, coalesced) ----
  {
    const float4* xg = (const float4*)(x0 + (size_t)b * 8192);
    float4* s4p = (float4*)sx;
#pragma unroll
    for (int i = 0; i < 8; ++i) s4p[i * TPB + tid] = xg[i * TPB + tid];
  }
  if (tid < 128) sw[tid] = w[tid];
  __syncthreads();

  const float wlo = sw[lane];
  const float whi = sw[lane + 64];
  const float scale = 0.08838834764831845f;  // 128^-0.5

  // scores for R rows of src (LDS, stride 128) -> ssc[soff + r]
  auto scores = [&](const float* src, int R, int soff) {
    const int rpw = R >> 2;  // rows per wave (4 waves)
    for (int j = 0; j < rpw; ++j) {
      const int r = wid * rpw + j;
      const float* row = src + r * 128;
      float p = row[lane] * wlo + row[lane + 64] * whi;
#pragma unroll
      for (int off = 32; off > 0; off >>= 1) p += __shfl_xor(p, off, 64);
      if (lane == 0) ssc[soff + r] = p * scale;
    }
  };
  // softmax over each group of 8 scores -> swt[soff + r]
  auto softmaxw = [&](int G, int soff) {
    if (tid < G * 8) {
      const int a = tid >> 3, k = tid & 7;
      const float* s = ssc + soff + a * 8;
      float m = s[0];
#pragma unroll
      for (int i = 1; i < 8; ++i) m = fmaxf(m, s[i]);
      float sum = 0.f, mine = 0.f;
#pragma unroll
      for (int i = 0; i < 8; ++i) {
        float e = __expf(s[i] - m);
        sum += e;
        if (i == k) mine = e;
      }
      swt[soff + tid] = mine / sum;
    }
  };
  // weighted sum: G groups of 8 rows from src -> ldst (optional) + gdst
  auto wsum = [&](const float* src, int G, int soff, float* ldst,
                  float* gdst) {
    const int n = G * 128;
    for (int i = 0; i < (n + TPB - 1) / TPB; ++i) {
      const int idx = i * TPB + tid;
      if (idx < n) {
        const int a = idx >> 7, c = idx & 127;
        const float* wt = swt + soff + a * 8;
        const float* s = src + a * 1024 + c;
        float acc = 0.f;
#pragma unroll
        for (int k = 0; k < 8; ++k) acc += wt[k] * s[k * 128];
        if (ldst) ldst[idx] = acc;
        gdst[idx] = acc;
      }
    }
  };

  // ---- Phase A: L1 (mean pairs of x) + L3 scores ----
  {
    float* g = out + O1 + (size_t)b * 4096;
#pragma unroll
    for (int i = 0; i < 16; ++i) {
      const int idx = i * TPB + tid;
      const int r2 = (idx >> 7) * 2, c = idx & 127;
      const float v = 0.5f * (sx[r2 * 128 + c] + sx[(r2 + 1) * 128 + c]);
      sl1[idx] = v;
      g[idx] = v;
    }
    scores(sx, 64, 0);
  }
  __syncthreads();

  // ---- Phase B: L2 (mean pairs of L1) + L3 softmax + L4 scores ----
  {
    float* g = out + O2 + (size_t)b * 2048;
#pragma unroll
    for (int i = 0; i < 8; ++i) {
      const int idx = i * TPB + tid;
      const int r2 = (idx >> 7) * 2, c = idx & 127;
      const float v = 0.5f * (sl1[r2 * 128 + c] + sl1[(r2 + 1) * 128 + c]);
      sl2[idx] = v;
      g[idx] = v;
    }
    softmaxw(8, 0);
    scores(sl1, 32, 64);
  }
  __syncthreads();

  // ---- Phase C: L3 output + L4 softmax + L5 scores ----
  wsum(sx, 8, 0, sl3, out + O3 + (size_t)b * 1024);
  softmaxw(4, 64);
  scores(sl2, 16, 96);
  __syncthreads();

  // ---- Phase D: L4 output + L5 softmax + L6 scores ----
  wsum(sl1, 4, 64, nullptr, out + O4 + (size_t)b * 512);
  softmaxw(2, 96);
  scores(sl3, 8, 112);
  __syncthreads();

  // ---- Phase E: L5 output + L6 softmax ----
  wsum(sl2, 2, 96, nullptr, out + O5 + (size_t)b * 256);
  softmaxw(1, 112);
  __syncthreads();

  // ---- Phase F: L6 output ----
  wsum(sl3, 1, 112, nullptr, out + O6 + (size_t)b * 128);
}

extern "C" void kernel_launch(void* const* d_in, const int* in_sizes, int n_in,
                              void* d_out, int out_size, void* d_ws,
                              size_t ws_size, hipStream_t stream) {
  const float* x0 = (const float*)d_in[0];
  const float* w = (const float*)d_in[1];
  float* out = (float*)d_out;
  const int n_leaves = in_sizes[0] / 128;  // 524288
  const int blocks = n_leaves / 64;        // 8192
  splat_fused<<<blocks, TPB, 0, stream>>>(x0, w, out);
}

// Round 2
// 104.200 us; speedup vs baseline: 2.1008x; 2.1008x over previous
//
#include <hip/hip_runtime.h>
#include <math.h>

// SplatCondenseNet fused tree pooling — register-resident version.
// Each block owns 64 consecutive leaves (one full L6 subtree).
// Thread layout: h = tid>>5 (slice 0..7) owns x rows 8h..8h+7 of the tile;
// cg = tid&31 owns columns 4cg..4cg+3 (float4 fragment).
// L1/L2: thread-local. L3: intra-slice shuffles. L4: intra-wave shuffles.
// L5/L6: one small LDS exchange (2 barriers total).
//
// Output layout (rows of 128 fp32, concat of layers 1..6):
//   L1 rows [0, 262144)  L2 [262144, 393216)  L3 [393216, 458752)
//   L4 [458752, 491520)  L5 [491520, 507904)  L6 [507904, 516096)

static constexpr size_t O1 = 0;
static constexpr size_t O2 = 262144ull * 128;
static constexpr size_t O3 = 393216ull * 128;
static constexpr size_t O4 = 458752ull * 128;
static constexpr size_t O5 = 491520ull * 128;
static constexpr size_t O6 = 507904ull * 128;

#define TPB 256

__device__ __forceinline__ float4 f4add(float4 a, float4 b) {
  return make_float4(a.x + b.x, a.y + b.y, a.z + b.z, a.w + b.w);
}
__device__ __forceinline__ float4 f4mul(float4 a, float s) {
  return make_float4(a.x * s, a.y * s, a.z * s, a.w * s);
}
__device__ __forceinline__ float4 f4fma(float4 a, float s, float4 c) {
  return make_float4(fmaf(a.x, s, c.x), fmaf(a.y, s, c.y), fmaf(a.z, s, c.z),
                     fmaf(a.w, s, c.w));
}
__device__ __forceinline__ float f4dot(float4 a, float4 b) {
  return a.x * b.x + a.y * b.y + a.z * b.z + a.w * b.w;
}
// sum across the 32-lane slice (lanes 0..31 or 32..63 of a wave)
__device__ __forceinline__ float slice_sum(float p) {
#pragma unroll
  for (int off = 16; off > 0; off >>= 1) p += __shfl_xor(p, off, 64);
  return p;
}

template <int N>
__device__ __forceinline__ void softmax_n(const float* s, float* wt) {
  float m = s[0];
#pragma unroll
  for (int i = 1; i < N; ++i) m = fmaxf(m, s[i]);
  float sum = 0.f;
#pragma unroll
  for (int i = 0; i < N; ++i) {
    wt[i] = __expf(s[i] - m);
    sum += wt[i];
  }
  const float inv = 1.f / sum;
#pragma unroll
  for (int i = 0; i < N; ++i) wt[i] *= inv;
}

__global__ __launch_bounds__(TPB, 4) void splat_fused(
    const float* __restrict__ x0, const float* __restrict__ w,
    float* __restrict__ out) {
  __shared__ float ssc[24];        // L5 scores [0..15], L6 scores [16..23]
  __shared__ float pb5[8][128];    // L5 per-slice partials
  __shared__ float pb6[8][128];    // L6 per-slice partials

  const int tid = threadIdx.x;
  const int h = tid >> 5;   // slice: owns x rows 8h..8h+7
  const int cg = tid & 31;  // column group
  const int c0 = cg << 2;
  const size_t b = blockIdx.x;
  const float scale = 0.08838834764831845f;  // 128^-0.5

  const float4 wv = *(const float4*)(w + c0);

  // ---- load 8 x float4 (coalesced) ----
  float4 xr[8];
  {
    const float* xb = x0 + b * 8192 + (size_t)(h * 8) * 128 + c0;
#pragma unroll
    for (int r = 0; r < 8; ++r) xr[r] = *(const float4*)(xb + r * 128);
  }

  // ---- L1: mean pairs (thread-local) ----
  float4 l1[4];
#pragma unroll
  for (int j = 0; j < 4; ++j)
    l1[j] = f4mul(f4add(xr[2 * j], xr[2 * j + 1]), 0.5f);
  {
    float* g = out + O1 + (b * 32 + h * 4) * 128 + c0;
#pragma unroll
    for (int j = 0; j < 4; ++j) *(float4*)(g + j * 128) = l1[j];
  }

  // ---- L2: mean pairs of L1 (thread-local) ----
  float4 l2[2];
#pragma unroll
  for (int j = 0; j < 2; ++j)
    l2[j] = f4mul(f4add(l1[2 * j], l1[2 * j + 1]), 0.5f);
  {
    float* g = out + O2 + (b * 16 + h * 2) * 128 + c0;
#pragma unroll
    for (int j = 0; j < 2; ++j) *(float4*)(g + j * 128) = l2[j];
  }

  // ---- L3: attention over x rows 8h..8h+7 (group == slice) ----
  float4 l3;
  {
    float s3[8];
#pragma unroll
    for (int r = 0; r < 8; ++r) s3[r] = slice_sum(f4dot(xr[r], wv)) * scale;
    float wt[8];
    softmax_n<8>(s3, wt);
    l3 = f4mul(xr[0], wt[0]);
#pragma unroll
    for (int r = 1; r < 8; ++r) l3 = f4fma(xr[r], wt[r], l3);
    *(float4*)(out + O3 + (b * 8 + h) * 128 + c0) = l3;
  }

  // ---- L4: attention over L1 rows (group == wave; slices 2g,2g+1) ----
  {
    float s8[8];
#pragma unroll
    for (int j = 0; j < 4; ++j) {
      const float sj = slice_sum(f4dot(l1[j], wv)) * scale;
      const float so = __shfl_xor(sj, 32, 64);
      if (h & 1) {
        s8[j] = so;
        s8[4 + j] = sj;
      } else {
        s8[j] = sj;
        s8[4 + j] = so;
      }
    }
    float wt[8];
    softmax_n<8>(s8, wt);
    const int base = (h & 1) * 4;
    float4 pa = f4mul(l1[0], wt[base]);
#pragma unroll
    for (int j = 1; j < 4; ++j) pa = f4fma(l1[j], wt[base + j], pa);
    pa.x += __shfl_xor(pa.x, 32, 64);
    pa.y += __shfl_xor(pa.y, 32, 64);
    pa.z += __shfl_xor(pa.z, 32, 64);
    pa.w += __shfl_xor(pa.w, 32, 64);
    if (!(h & 1))
      *(float4*)(out + O4 + (b * 4 + (h >> 1)) * 128 + c0) = pa;
  }

  // ---- L5 & L6 scores -> LDS ----
  {
#pragma unroll
    for (int j = 0; j < 2; ++j) {
      const float sj = slice_sum(f4dot(l2[j], wv)) * scale;
      if (cg == j) ssc[h * 2 + j] = sj;  // block-local l2 row 2h+j
    }
    const float s6 = slice_sum(f4dot(l3, wv)) * scale;
    if (cg == 2) ssc[16 + h] = s6;  // block-local l3 row h
  }
  __syncthreads();

  // ---- L5/L6 partial weighted sums -> LDS ----
  {
    float wt5[8];
    softmax_n<8>(ssc + (h >> 2) * 8, wt5);  // group g5 = h>>2
    const int base = (h & 3) * 2;           // my l2 rows within group
    const float4 pa5 = f4fma(l2[1], wt5[base + 1], f4mul(l2[0], wt5[base]));
    *(float4*)(&pb5[h][c0]) = pa5;

    float wt6[8];
    softmax_n<8>(ssc + 16, wt6);
    *(float4*)(&pb6[h][c0]) = f4mul(l3, wt6[h]);
  }
  __syncthreads();

  // ---- combine + store L5 (256 vals), L6 (128 vals) ----
  {
    const int g = tid >> 7, c = tid & 127;
    const float v = pb5[g * 4 + 0][c] + pb5[g * 4 + 1][c] +
                    pb5[g * 4 + 2][c] + pb5[g * 4 + 3][c];
    out[O5 + (b * 2 + g) * 128 + c] = v;
  }
  if (tid < 128) {
    float v = 0.f;
#pragma unroll
    for (int s = 0; s < 8; ++s) v += pb6[s][tid];
    out[O6 + b * 128 + tid] = v;
  }
}

extern "C" void kernel_launch(void* const* d_in, const int* in_sizes, int n_in,
                              void* d_out, int out_size, void* d_ws,
                              size_t ws_size, hipStream_t stream) {
  const float* x0 = (const float*)d_in[0];
  const float* w = (const float*)d_in[1];
  float* out = (float*)d_out;
  const int n_leaves = in_sizes[0] / 128;  // 524288
  const int blocks = n_leaves / 64;        // 8192
  splat_fused<<<blocks, TPB, 0, stream>>>(x0, w, out);
}

// Round 3
// 86.771 us; speedup vs baseline: 2.5228x; 1.2009x over previous
//
#include <hip/hip_runtime.h>
#include <math.h>

// SplatCondenseNet fused tree pooling — register-resident + non-temporal
// output stores. Each block owns 64 consecutive leaves (one L6 subtree).
// Thread layout: h = tid>>5 (slice 0..7) owns x rows 8h..8h+7 of the tile;
// cg = tid&31 owns columns 4cg..4cg+3 (float4 fragment).
// L1/L2: thread-local. L3: intra-slice shuffles. L4: intra-wave shuffles.
// L5/L6: one small LDS exchange (2 barriers total).
// Outputs are write-once/never-read -> nontemporal stores keep x0 resident
// in Infinity Cache across graph replays (cuts HBM FETCH).
//
// Output layout (rows of 128 fp32, concat of layers 1..6):
//   L1 rows [0, 262144)  L2 [262144, 393216)  L3 [393216, 458752)
//   L4 [458752, 491520)  L5 [491520, 507904)  L6 [507904, 516096)

static constexpr size_t O1 = 0;
static constexpr size_t O2 = 262144ull * 128;
static constexpr size_t O3 = 393216ull * 128;
static constexpr size_t O4 = 458752ull * 128;
static constexpr size_t O5 = 491520ull * 128;
static constexpr size_t O6 = 507904ull * 128;

#define TPB 256

typedef float f4v __attribute__((ext_vector_type(4)));

__device__ __forceinline__ float4 f4add(float4 a, float4 b) {
  return make_float4(a.x + b.x, a.y + b.y, a.z + b.z, a.w + b.w);
}
__device__ __forceinline__ float4 f4mul(float4 a, float s) {
  return make_float4(a.x * s, a.y * s, a.z * s, a.w * s);
}
__device__ __forceinline__ float4 f4fma(float4 a, float s, float4 c) {
  return make_float4(fmaf(a.x, s, c.x), fmaf(a.y, s, c.y), fmaf(a.z, s, c.z),
                     fmaf(a.w, s, c.w));
}
__device__ __forceinline__ float f4dot(float4 a, float4 b) {
  return a.x * b.x + a.y * b.y + a.z * b.z + a.w * b.w;
}
__device__ __forceinline__ void st_nt_f4(float* p, float4 v) {
  f4v t;
  t.x = v.x; t.y = v.y; t.z = v.z; t.w = v.w;
  __builtin_nontemporal_store(t, (f4v*)p);
}
__device__ __forceinline__ void st_nt_f1(float* p, float v) {
  __builtin_nontemporal_store(v, p);
}
// sum across the 32-lane slice (lanes 0..31 or 32..63 of a wave)
__device__ __forceinline__ float slice_sum(float p) {
#pragma unroll
  for (int off = 16; off > 0; off >>= 1) p += __shfl_xor(p, off, 64);
  return p;
}

template <int N>
__device__ __forceinline__ void softmax_n(const float* s, float* wt) {
  float m = s[0];
#pragma unroll
  for (int i = 1; i < N; ++i) m = fmaxf(m, s[i]);
  float sum = 0.f;
#pragma unroll
  for (int i = 0; i < N; ++i) {
    wt[i] = __expf(s[i] - m);
    sum += wt[i];
  }
  const float inv = 1.f / sum;
#pragma unroll
  for (int i = 0; i < N; ++i) wt[i] *= inv;
}

__global__ __launch_bounds__(TPB, 4) void splat_fused(
    const float* __restrict__ x0, const float* __restrict__ w,
    float* __restrict__ out) {
  __shared__ float ssc[24];      // L5 scores [0..15], L6 scores [16..23]
  __shared__ float pb5[8][128];  // L5 per-slice partials
  __shared__ float pb6[8][128];  // L6 per-slice partials

  const int tid = threadIdx.x;
  const int h = tid >> 5;   // slice: owns x rows 8h..8h+7
  const int cg = tid & 31;  // column group
  const int c0 = cg << 2;
  const size_t b = blockIdx.x;
  const float scale = 0.08838834764831845f;  // 128^-0.5

  const float4 wv = *(const float4*)(w + c0);

  // ---- load 8 x float4 (coalesced, cached: want L3 retention) ----
  float4 xr[8];
  {
    const float* xb = x0 + b * 8192 + (size_t)(h * 8) * 128 + c0;
#pragma unroll
    for (int r = 0; r < 8; ++r) xr[r] = *(const float4*)(xb + r * 128);
  }

  // ---- L1: mean pairs (thread-local) ----
  float4 l1[4];
#pragma unroll
  for (int j = 0; j < 4; ++j)
    l1[j] = f4mul(f4add(xr[2 * j], xr[2 * j + 1]), 0.5f);
  {
    float* g = out + O1 + (b * 32 + h * 4) * 128 + c0;
#pragma unroll
    for (int j = 0; j < 4; ++j) st_nt_f4(g + j * 128, l1[j]);
  }

  // ---- L2: mean pairs of L1 (thread-local) ----
  float4 l2[2];
#pragma unroll
  for (int j = 0; j < 2; ++j)
    l2[j] = f4mul(f4add(l1[2 * j], l1[2 * j + 1]), 0.5f);
  {
    float* g = out + O2 + (b * 16 + h * 2) * 128 + c0;
#pragma unroll
    for (int j = 0; j < 2; ++j) st_nt_f4(g + j * 128, l2[j]);
  }

  // ---- L3: attention over x rows 8h..8h+7 (group == slice) ----
  float4 l3;
  {
    float s3[8];
#pragma unroll
    for (int r = 0; r < 8; ++r) s3[r] = slice_sum(f4dot(xr[r], wv)) * scale;
    float wt[8];
    softmax_n<8>(s3, wt);
    l3 = f4mul(xr[0], wt[0]);
#pragma unroll
    for (int r = 1; r < 8; ++r) l3 = f4fma(xr[r], wt[r], l3);
    st_nt_f4(out + O3 + (b * 8 + h) * 128 + c0, l3);
  }

  // ---- L4: attention over L1 rows (group == wave; slices 2g,2g+1) ----
  {
    float s8[8];
#pragma unroll
    for (int j = 0; j < 4; ++j) {
      const float sj = slice_sum(f4dot(l1[j], wv)) * scale;
      const float so = __shfl_xor(sj, 32, 64);
      if (h & 1) {
        s8[j] = so;
        s8[4 + j] = sj;
      } else {
        s8[j] = sj;
        s8[4 + j] = so;
      }
    }
    float wt[8];
    softmax_n<8>(s8, wt);
    const int base = (h & 1) * 4;
    float4 pa = f4mul(l1[0], wt[base]);
#pragma unroll
    for (int j = 1; j < 4; ++j) pa = f4fma(l1[j], wt[base + j], pa);
    pa.x += __shfl_xor(pa.x, 32, 64);
    pa.y += __shfl_xor(pa.y, 32, 64);
    pa.z += __shfl_xor(pa.z, 32, 64);
    pa.w += __shfl_xor(pa.w, 32, 64);
    if (!(h & 1)) st_nt_f4(out + O4 + (b * 4 + (h >> 1)) * 128 + c0, pa);
  }

  // ---- L5 & L6 scores -> LDS ----
  {
#pragma unroll
    for (int j = 0; j < 2; ++j) {
      const float sj = slice_sum(f4dot(l2[j], wv)) * scale;
      if (cg == j) ssc[h * 2 + j] = sj;  // block-local l2 row 2h+j
    }
    const float s6 = slice_sum(f4dot(l3, wv)) * scale;
    if (cg == 2) ssc[16 + h] = s6;  // block-local l3 row h
  }
  __syncthreads();

  // ---- L5/L6 partial weighted sums -> LDS ----
  {
    float wt5[8];
    softmax_n<8>(ssc + (h >> 2) * 8, wt5);  // group g5 = h>>2
    const int base = (h & 3) * 2;           // my l2 rows within group
    const float4 pa5 = f4fma(l2[1], wt5[base + 1], f4mul(l2[0], wt5[base]));
    *(float4*)(&pb5[h][c0]) = pa5;

    float wt6[8];
    softmax_n<8>(ssc + 16, wt6);
    *(float4*)(&pb6[h][c0]) = f4mul(l3, wt6[h]);
  }
  __syncthreads();

  // ---- combine + store L5 (256 vals), L6 (128 vals) ----
  {
    const int g = tid >> 7, c = tid & 127;
    const float v = pb5[g * 4 + 0][c] + pb5[g * 4 + 1][c] +
                    pb5[g * 4 + 2][c] + pb5[g * 4 + 3][c];
    st_nt_f1(out + O5 + (b * 2 + g) * 128 + c, v);
  }
  if (tid < 128) {
    float v = 0.f;
#pragma unroll
    for (int s = 0; s < 8; ++s) v += pb6[s][tid];
    st_nt_f1(out + O6 + b * 128 + tid, v);
  }
}

extern "C" void kernel_launch(void* const* d_in, const int* in_sizes, int n_in,
                              void* d_out, int out_size, void* d_ws,
                              size_t ws_size, hipStream_t stream) {
  const float* x0 = (const float*)d_in[0];
  const float* w = (const float*)d_in[1];
  float* out = (float*)d_out;
  const int n_leaves = in_sizes[0] / 128;  // 524288
  const int blocks = n_leaves / 64;        // 8192
  splat_fused<<<blocks, TPB, 0, stream>>>(x0, w, out);
}

// Round 4
// 86.603 us; speedup vs baseline: 2.5277x; 1.0019x over previous
//
#include <hip/hip_runtime.h>
#include <math.h>

// SplatCondenseNet fused tree pooling — register-resident, phase-reordered.
// Each block owns 64 consecutive leaves (one full L6 subtree).
// Thread layout: h = tid>>5 (slice 0..7) owns x rows 8h..8h+7 of the tile;
// cg = tid&31 owns columns 4cg..4cg+3 (float4 fragment).
//
// Phase order is chosen to MINIMIZE xr's live range so the compiler keeps it
// in registers instead of re-loading from global (round-3 pathology:
// VGPR_Count=36 proved rematerialization):
//   load xr -> L3 (attention over xr) -> L1 = mean(xr)  [xr dead]
//   -> L2 = mean(L1), L4 (attention over L1) [l1 dead]
//   -> L5/L6 via one small LDS exchange (2 barriers).
// All outputs stored non-temporally (write-once, never re-read).
//
// Output layout (rows of 128 fp32, concat of layers 1..6):
//   L1 rows [0, 262144)  L2 [262144, 393216)  L3 [393216, 458752)
//   L4 [458752, 491520)  L5 [491520, 507904)  L6 [507904, 516096)

static constexpr size_t O1 = 0;
static constexpr size_t O2 = 262144ull * 128;
static constexpr size_t O3 = 393216ull * 128;
static constexpr size_t O4 = 458752ull * 128;
static constexpr size_t O5 = 491520ull * 128;
static constexpr size_t O6 = 507904ull * 128;

#define TPB 256

typedef float f4v __attribute__((ext_vector_type(4)));

__device__ __forceinline__ float4 f4add(float4 a, float4 b) {
  return make_float4(a.x + b.x, a.y + b.y, a.z + b.z, a.w + b.w);
}
__device__ __forceinline__ float4 f4mul(float4 a, float s) {
  return make_float4(a.x * s, a.y * s, a.z * s, a.w * s);
}
__device__ __forceinline__ float4 f4fma(float4 a, float s, float4 c) {
  return make_float4(fmaf(a.x, s, c.x), fmaf(a.y, s, c.y), fmaf(a.z, s, c.z),
                     fmaf(a.w, s, c.w));
}
__device__ __forceinline__ float f4dot(float4 a, float4 b) {
  return a.x * b.x + a.y * b.y + a.z * b.z + a.w * b.w;
}
__device__ __forceinline__ void st_nt_f4(float* p, float4 v) {
  f4v t;
  t.x = v.x; t.y = v.y; t.z = v.z; t.w = v.w;
  __builtin_nontemporal_store(t, (f4v*)p);
}
__device__ __forceinline__ void st_nt_f1(float* p, float v) {
  __builtin_nontemporal_store(v, p);
}
// sum across the 32-lane slice (lanes 0..31 or 32..63 of a wave)
__device__ __forceinline__ float slice_sum(float p) {
#pragma unroll
  for (int off = 16; off > 0; off >>= 1) p += __shfl_xor(p, off, 64);
  return p;
}

template <int N>
__device__ __forceinline__ void softmax_n(const float* s, float* wt) {
  float m = s[0];
#pragma unroll
  for (int i = 1; i < N; ++i) m = fmaxf(m, s[i]);
  float sum = 0.f;
#pragma unroll
  for (int i = 0; i < N; ++i) {
    wt[i] = __expf(s[i] - m);
    sum += wt[i];
  }
  const float inv = 1.f / sum;
#pragma unroll
  for (int i = 0; i < N; ++i) wt[i] *= inv;
}

__global__ __launch_bounds__(TPB, 2) void splat_fused(
    const float* __restrict__ x0, const float* __restrict__ w,
    float* __restrict__ out) {
  __shared__ float ssc[24];      // L5 scores [0..15], L6 scores [16..23]
  __shared__ float pb5[8][128];  // L5 per-slice partials
  __shared__ float pb6[8][128];  // L6 per-slice partials

  const int tid = threadIdx.x;
  const int h = tid >> 5;   // slice: owns x rows 8h..8h+7
  const int cg = tid & 31;  // column group
  const int c0 = cg << 2;
  const size_t b = blockIdx.x;
  const float scale = 0.08838834764831845f;  // 128^-0.5

  const float4 wv = *(const float4*)(w + c0);

  // ---- load 8 x float4 (coalesced, cached) ----
  float4 xr[8];
  {
    const float* xb = x0 + b * 8192 + (size_t)(h * 8) * 128 + c0;
#pragma unroll
    for (int r = 0; r < 8; ++r) xr[r] = *(const float4*)(xb + r * 128);
  }

  // ---- L3 FIRST (while xr is hot): attention over x rows 8h..8h+7 ----
  float4 l3;
  {
    float s3[8];
#pragma unroll
    for (int r = 0; r < 8; ++r) s3[r] = slice_sum(f4dot(xr[r], wv)) * scale;
    float wt[8];
    softmax_n<8>(s3, wt);
    l3 = f4mul(xr[0], wt[0]);
#pragma unroll
    for (int r = 1; r < 8; ++r) l3 = f4fma(xr[r], wt[r], l3);
    st_nt_f4(out + O3 + (b * 8 + h) * 128 + c0, l3);
  }

  // ---- L1: mean pairs (consumes xr; xr dead after this) ----
  float4 l1[4];
#pragma unroll
  for (int j = 0; j < 4; ++j)
    l1[j] = f4mul(f4add(xr[2 * j], xr[2 * j + 1]), 0.5f);
  {
    float* g = out + O1 + (b * 32 + h * 4) * 128 + c0;
#pragma unroll
    for (int j = 0; j < 4; ++j) st_nt_f4(g + j * 128, l1[j]);
  }

  // ---- L2: mean pairs of L1 ----
  float4 l2[2];
#pragma unroll
  for (int j = 0; j < 2; ++j)
    l2[j] = f4mul(f4add(l1[2 * j], l1[2 * j + 1]), 0.5f);
  {
    float* g = out + O2 + (b * 16 + h * 2) * 128 + c0;
#pragma unroll
    for (int j = 0; j < 2; ++j) st_nt_f4(g + j * 128, l2[j]);
  }

  // ---- L4: attention over L1 rows (group == wave; slices 2g,2g+1) ----
  {
    float s8[8];
#pragma unroll
    for (int j = 0; j < 4; ++j) {
      const float sj = slice_sum(f4dot(l1[j], wv)) * scale;
      const float so = __shfl_xor(sj, 32, 64);
      if (h & 1) {
        s8[j] = so;
        s8[4 + j] = sj;
      } else {
        s8[j] = sj;
        s8[4 + j] = so;
      }
    }
    float wt[8];
    softmax_n<8>(s8, wt);
    const int base = (h & 1) * 4;
    float4 pa = f4mul(l1[0], wt[base]);
#pragma unroll
    for (int j = 1; j < 4; ++j) pa = f4fma(l1[j], wt[base + j], pa);
    pa.x += __shfl_xor(pa.x, 32, 64);
    pa.y += __shfl_xor(pa.y, 32, 64);
    pa.z += __shfl_xor(pa.z, 32, 64);
    pa.w += __shfl_xor(pa.w, 32, 64);
    if (!(h & 1)) st_nt_f4(out + O4 + (b * 4 + (h >> 1)) * 128 + c0, pa);
  }

  // ---- L5 & L6 scores -> LDS ----
  {
#pragma unroll
    for (int j = 0; j < 2; ++j) {
      const float sj = slice_sum(f4dot(l2[j], wv)) * scale;
      if (cg == j) ssc[h * 2 + j] = sj;  // block-local l2 row 2h+j
    }
    const float s6 = slice_sum(f4dot(l3, wv)) * scale;
    if (cg == 2) ssc[16 + h] = s6;  // block-local l3 row h
  }
  __syncthreads();

  // ---- L5/L6 partial weighted sums -> LDS ----
  {
    float wt5[8];
    softmax_n<8>(ssc + (h >> 2) * 8, wt5);  // group g5 = h>>2
    const int base = (h & 3) * 2;           // my l2 rows within group
    const float4 pa5 = f4fma(l2[1], wt5[base + 1], f4mul(l2[0], wt5[base]));
    *(float4*)(&pb5[h][c0]) = pa5;

    float wt6[8];
    softmax_n<8>(ssc + 16, wt6);
    *(float4*)(&pb6[h][c0]) = f4mul(l3, wt6[h]);
  }
  __syncthreads();

  // ---- combine + store L5 (256 vals), L6 (128 vals) ----
  {
    const int g = tid >> 7, c = tid & 127;
    const float v = pb5[g * 4 + 0][c] + pb5[g * 4 + 1][c] +
                    pb5[g * 4 + 2][c] + pb5[g * 4 + 3][c];
    st_nt_f1(out + O5 + (b * 2 + g) * 128 + c, v);
  }
  if (tid < 128) {
    float v = 0.f;
#pragma unroll
    for (int s = 0; s < 8; ++s) v += pb6[s][tid];
    st_nt_f1(out + O6 + b * 128 + tid, v);
  }
}

extern "C" void kernel_launch(void* const* d_in, const int* in_sizes, int n_in,
                              void* d_out, int out_size, void* d_ws,
                              size_t ws_size, hipStream_t stream) {
  const float* x0 = (const float*)d_in[0];
  const float* w = (const float*)d_in[1];
  float* out = (float*)d_out;
  const int n_leaves = in_sizes[0] / 128;  // 524288
  const int blocks = n_leaves / 64;        // 8192
  splat_fused<<<blocks, TPB, 0, stream>>>(x0, w, out);
}